// Round 1
// baseline (448.616 us; speedup 1.0000x reference)
//
#include <hip/hip_runtime.h>
#include <stdint.h>

#define NN 65536
#define BB 64
#define NP 4

// Exact-fp32 squared distance, matching numpy's ((dx*dx + dy*dy) + dz*dz)
// with no FMA contraction (rn intrinsics are never fused).
__device__ __forceinline__ float sqdist(float x, float y, float z,
                                        float cx, float cy, float cz) {
    float dx = __fsub_rn(x, cx);
    float dy = __fsub_rn(y, cy);
    float dz = __fsub_rn(z, cz);
    return __fadd_rn(__fadd_rn(__fmul_rn(dx, dx), __fmul_rn(dy, dy)),
                     __fmul_rn(dz, dz));
}

// K1: furthest point sampling. One 1024-thread block per batch.
// min_d lives in 64 registers per thread (point i = k*1024 + tid).
// Argmax tie-break: first (smallest) index, matching np.argmax.
__global__ __launch_bounds__(1024, 4) void fps_kernel(
        const float* __restrict__ pts, float* __restrict__ centers) {
    const int b = blockIdx.x;
    const int tid = threadIdx.x;
    const float* base = pts + (size_t)b * NN * 6;
    __shared__ float s_c[3];
    __shared__ float s_bv[16];
    __shared__ int   s_bi[16];
    if (tid == 0) { s_c[0] = base[0]; s_c[1] = base[1]; s_c[2] = base[2]; }
    __syncthreads();

    float mind[64];
    #pragma unroll
    for (int k = 0; k < 64; ++k) mind[k] = 1e10f;  // matches jnp 1e10 init

    for (int it = 0; it < NP; ++it) {
        float cx = s_c[0], cy = s_c[1], cz = s_c[2];
        if (tid == 0) {
            centers[(b * NP + it) * 3 + 0] = cx;
            centers[(b * NP + it) * 3 + 1] = cy;
            centers[(b * NP + it) * 3 + 2] = cz;
        }
        float bestv = -1.0f;
        int   besti = 0;
        #pragma unroll
        for (int k = 0; k < 64; ++k) {
            int i = (k << 10) + tid;
            const float* p = base + (size_t)i * 6;
            float d = sqdist(p[0], p[1], p[2], cx, cy, cz);
            float m = fminf(mind[k], d);
            mind[k] = m;
            if (m > bestv) { bestv = m; besti = i; }  // strict > keeps earliest i
        }
        // wave reduction: max value, min index on ties
        #pragma unroll
        for (int off = 32; off > 0; off >>= 1) {
            float ov = __shfl_down(bestv, off, 64);
            int   oi = __shfl_down(besti, off, 64);
            if (ov > bestv || (ov == bestv && oi < besti)) { bestv = ov; besti = oi; }
        }
        const int lane = tid & 63, wid = tid >> 6;
        if (lane == 0) { s_bv[wid] = bestv; s_bi[wid] = besti; }
        __syncthreads();
        if (tid == 0) {
            float bv = s_bv[0]; int bi = s_bi[0];
            for (int w = 1; w < 16; ++w) {
                float v = s_bv[w]; int i2 = s_bi[w];
                if (v > bv || (v == bv && i2 < bi)) { bv = v; bi = i2; }
            }
            const float* p = base + (size_t)bi * 6;
            s_c[0] = p[0]; s_c[1] = p[1]; s_c[2] = p[2];
        }
        __syncthreads();
    }
}

// K2: keep-mask + stable compaction. One 1024-thread block per batch;
// thread t owns contiguous points [t*64, t*64+64) so scan order == index order.
__global__ __launch_bounds__(1024) void compact_kernel(
        const float* __restrict__ pts, const float* __restrict__ centers,
        int* __restrict__ valid, int* __restrict__ numvalid) {
    const int b = blockIdx.x;
    const int tid = threadIdx.x;
    const float* base = pts + (size_t)b * NN * 6;
    __shared__ float s_c[NP * 3];
    __shared__ int s_wsum[16];
    __shared__ int s_woff[16];
    if (tid < NP * 3) s_c[tid] = centers[b * NP * 3 + tid];
    __syncthreads();
    const float c0x = s_c[0], c0y = s_c[1],  c0z = s_c[2];
    const float c1x = s_c[3], c1y = s_c[4],  c1z = s_c[5];
    const float c2x = s_c[6], c2y = s_c[7],  c2z = s_c[8];
    const float c3x = s_c[9], c3y = s_c[10], c3z = s_c[11];

    const int i0 = tid << 6;
    uint64_t mask = 0;
    int cnt = 0;
    for (int k = 0; k < 64; ++k) {
        const float* p = base + (size_t)(i0 + k) * 6;
        float x = p[0], y = p[1], z = p[2];
        float d0 = __fsqrt_rn(sqdist(x, y, z, c0x, c0y, c0z));
        float d1 = __fsqrt_rn(sqdist(x, y, z, c1x, c1y, c1z));
        float d2 = __fsqrt_rn(sqdist(x, y, z, c2x, c2y, c2z));
        float d3 = __fsqrt_rn(sqdist(x, y, z, c3x, c3y, c3z));
        float md = fminf(fminf(d0, d1), fminf(d2, d3));
        int keep = (md >= 0.2f) ? 1 : 0;
        mask |= ((uint64_t)keep) << k;
        cnt += keep;
    }
    // block exclusive scan of per-thread counts
    const int lane = tid & 63, wid = tid >> 6;
    int incl = cnt;
    #pragma unroll
    for (int off = 1; off < 64; off <<= 1) {
        int v = __shfl_up(incl, off, 64);
        if (lane >= off) incl += v;
    }
    if (lane == 63) s_wsum[wid] = incl;
    __syncthreads();
    if (tid == 0) {
        int run = 0;
        for (int w = 0; w < 16; ++w) { s_woff[w] = run; run += s_wsum[w]; }
        numvalid[b] = run;
    }
    __syncthreads();
    int pos = s_woff[wid] + incl - cnt;
    int* vb = valid + ((size_t)b << 16);
    for (int k = 0; k < 64; ++k) {
        if ((mask >> k) & 1ull) { vb[pos++] = i0 + k; }
    }
}

// K3: cyclic gather of kept points into the output.
__global__ __launch_bounds__(256) void gather_kernel(
        const float* __restrict__ pts, const int* __restrict__ valid,
        const int* __restrict__ numvalid, float* __restrict__ out) {
    const int idx = blockIdx.x * 256 + threadIdx.x;  // over B*N
    const int b = idx >> 16;
    const int j = idx & (NN - 1);
    const int nv = numvalid[b];
    float2* o = (float2*)(out + (size_t)idx * 6);   // 24B stride -> 8B aligned
    if (nv <= 0) {
        float2 z = make_float2(0.f, 0.f);
        o[0] = z; o[1] = z; o[2] = z;
        return;
    }
    unsigned jj = (unsigned)j % (unsigned)nv;
    int src = valid[((size_t)b << 16) + jj];
    const float2* p = (const float2*)(pts + ((size_t)(b << 16) + (size_t)src) * 6);
    o[0] = p[0]; o[1] = p[1]; o[2] = p[2];
}

extern "C" void kernel_launch(void* const* d_in, const int* in_sizes, int n_in,
                              void* d_out, int out_size, void* d_ws, size_t ws_size,
                              hipStream_t stream) {
    const float* pts = (const float*)d_in[0];
    float* out = (float*)d_out;

    float* centers  = (float*)d_ws;                       // 64*4*3 floats
    int*   numvalid = (int*)((char*)d_ws + 4096);         // 64 ints
    int*   valid    = (int*)((char*)d_ws + 8192);         // 64*65536 ints = 16 MB

    fps_kernel<<<BB, 1024, 0, stream>>>(pts, centers);
    compact_kernel<<<BB, 1024, 0, stream>>>(pts, centers, valid, numvalid);
    gather_kernel<<<(BB * NN) / 256, 256, 0, stream>>>(pts, valid, numvalid, out);
}

// Round 2
// 300.260 us; speedup vs baseline: 1.4941x; 1.4941x over previous
//
#include <hip/hip_runtime.h>
#include <stdint.h>

#define NN 65536
#define BB 64
#define NP 4
#define TPB 256
#define BPB (NN / TPB)   // 256 blocks per batch

// Exact-fp32 squared distance, matching numpy's ((dx*dx + dy*dy) + dz*dz)
// with no FMA contraction (rn intrinsics are never fused).
__device__ __forceinline__ float sqdist(float x, float y, float z,
                                        float cx, float cy, float cz) {
    float dx = __fsub_rn(x, cx);
    float dy = __fsub_rn(y, cy);
    float dz = __fsub_rn(z, cz);
    return __fadd_rn(__fadd_rn(__fmul_rn(dx, dx), __fmul_rn(dy, dy)),
                     __fmul_rn(dz, dz));
}

// Block-level argmax (max value, smallest index on ties -> np.argmax semantics),
// result written by thread 0 to partV/partI[gb].
__device__ __forceinline__ void block_argmax(float v, int i, float* partV,
                                             int* partI, int gb) {
    __shared__ float s_v[4];
    __shared__ int   s_i[4];
    const int tid = threadIdx.x;
    const int lane = tid & 63, wid = tid >> 6;
    #pragma unroll
    for (int off = 32; off > 0; off >>= 1) {
        float ov = __shfl_down(v, off, 64);
        int   oi = __shfl_down(i, off, 64);
        if (ov > v || (ov == v && oi < i)) { v = ov; i = oi; }
    }
    if (lane == 0) { s_v[wid] = v; s_i[wid] = i; }
    __syncthreads();
    if (tid == 0) {
        float bv = s_v[0]; int bi = s_i[0];
        #pragma unroll
        for (int w = 1; w < 4; ++w) {
            float vv = s_v[w]; int ii = s_i[w];
            if (vv > bv || (vv == bv && ii < bi)) { bv = vv; bi = ii; }
        }
        partV[gb] = bv; partI[gb] = bi;
    }
}

// Pass 1: distance to point 0 (the first FPS center), init mind, optionally
// write packed xyz, per-block argmax partials. One point per thread.
__global__ __launch_bounds__(TPB) void fps_init_kernel(
        const float* __restrict__ pts, float* __restrict__ mind,
        float* __restrict__ pxyz, float* __restrict__ partV,
        int* __restrict__ partI) {
    const int gb = blockIdx.x;
    const int b = gb >> 8, blk = gb & 255;
    const float* base = pts + (size_t)b * NN * 6;
    const float cx = base[0], cy = base[1], cz = base[2];
    const int i = (blk << 8) + threadIdx.x;
    const float* p = base + (size_t)i * 6;
    const float x = p[0], y = p[1], z = p[2];
    const float d = sqdist(x, y, z, cx, cy, cz);
    const float m = fminf(1e10f, d);
    mind[(size_t)b * NN + i] = m;
    if (pxyz) {
        float* q = pxyz + ((size_t)b * NN + i) * 3;
        q[0] = x; q[1] = y; q[2] = z;
    }
    block_argmax(m, i, partV, partI, gb);
}

// Update pass: mind = min(mind, dist to current center); optional argmax.
__global__ __launch_bounds__(TPB) void fps_upd_kernel(
        const float* __restrict__ xyz, int stride,
        const float* __restrict__ cur, float* __restrict__ mind,
        float* __restrict__ partV, int* __restrict__ partI, int doArg) {
    const int gb = blockIdx.x;
    const int b = gb >> 8, blk = gb & 255;
    const float cx = cur[b * 3 + 0], cy = cur[b * 3 + 1], cz = cur[b * 3 + 2];
    const int i = (blk << 8) + threadIdx.x;
    const size_t idx = (size_t)b * NN + i;
    const float* p = xyz + idx * (size_t)stride;
    const float d = sqdist(p[0], p[1], p[2], cx, cy, cz);
    const float m = fminf(mind[idx], d);
    mind[idx] = m;
    if (doArg) block_argmax(m, i, partV, partI, gb);
}

// Reduce 256 per-block partials of one batch -> next center's xyz.
__global__ __launch_bounds__(TPB) void fps_reduce_kernel(
        const float* __restrict__ partV, const int* __restrict__ partI,
        const float* __restrict__ xyz, int stride, float* __restrict__ cur) {
    const int b = blockIdx.x;
    const int tid = threadIdx.x;
    float v = partV[b * BPB + tid];
    int   i = partI[b * BPB + tid];
    __shared__ float s_v[4];
    __shared__ int   s_i[4];
    const int lane = tid & 63, wid = tid >> 6;
    #pragma unroll
    for (int off = 32; off > 0; off >>= 1) {
        float ov = __shfl_down(v, off, 64);
        int   oi = __shfl_down(i, off, 64);
        if (ov > v || (ov == v && oi < i)) { v = ov; i = oi; }
    }
    if (lane == 0) { s_v[wid] = v; s_i[wid] = i; }
    __syncthreads();
    if (tid == 0) {
        float bv = s_v[0]; int bi = s_i[0];
        #pragma unroll
        for (int w = 1; w < 4; ++w) {
            float vv = s_v[w]; int ii = s_i[w];
            if (vv > bv || (vv == bv && ii < bi)) { bv = vv; bi = ii; }
        }
        const float* p = xyz + ((size_t)b * NN + bi) * (size_t)stride;
        cur[b * 3 + 0] = p[0]; cur[b * 3 + 1] = p[1]; cur[b * 3 + 2] = p[2];
    }
}

// Stable compaction from final mind (min squared distance to all 4 centers).
// sqrt is monotone + correctly rounded: sqrt_rn(min d^2) == min(norm).
__global__ __launch_bounds__(1024) void compact_kernel(
        const float* __restrict__ mind, int* __restrict__ valid,
        int* __restrict__ numvalid) {
    const int b = blockIdx.x;
    const int tid = threadIdx.x;
    const int i0 = tid << 6;
    const float4* mb = (const float4*)(mind + (size_t)b * NN + i0);
    __shared__ int s_wsum[16];
    __shared__ int s_woff[16];
    uint64_t mask = 0;
    int cnt = 0;
    #pragma unroll
    for (int k = 0; k < 16; ++k) {
        float4 v = mb[k];
        int k0 = (__fsqrt_rn(v.x) >= 0.2f) ? 1 : 0;
        int k1 = (__fsqrt_rn(v.y) >= 0.2f) ? 1 : 0;
        int k2 = (__fsqrt_rn(v.z) >= 0.2f) ? 1 : 0;
        int k3 = (__fsqrt_rn(v.w) >= 0.2f) ? 1 : 0;
        mask |= ((uint64_t)k0) << (4 * k + 0);
        mask |= ((uint64_t)k1) << (4 * k + 1);
        mask |= ((uint64_t)k2) << (4 * k + 2);
        mask |= ((uint64_t)k3) << (4 * k + 3);
        cnt += k0 + k1 + k2 + k3;
    }
    const int lane = tid & 63, wid = tid >> 6;
    int incl = cnt;
    #pragma unroll
    for (int off = 1; off < 64; off <<= 1) {
        int v = __shfl_up(incl, off, 64);
        if (lane >= off) incl += v;
    }
    if (lane == 63) s_wsum[wid] = incl;
    __syncthreads();
    if (tid == 0) {
        int run = 0;
        for (int w = 0; w < 16; ++w) { s_woff[w] = run; run += s_wsum[w]; }
        numvalid[b] = run;
    }
    __syncthreads();
    int pos = s_woff[wid] + incl - cnt;
    int* vb = valid + ((size_t)b << 16);
    for (int k = 0; k < 64; ++k) {
        if ((mask >> k) & 1ull) { vb[pos++] = i0 + k; }
    }
}

// Cyclic gather of kept points into the output.
__global__ __launch_bounds__(256) void gather_kernel(
        const float* __restrict__ pts, const int* __restrict__ valid,
        const int* __restrict__ numvalid, float* __restrict__ out) {
    const int idx = blockIdx.x * 256 + threadIdx.x;  // over B*N
    const int b = idx >> 16;
    const int j = idx & (NN - 1);
    const int nv = numvalid[b];
    float2* o = (float2*)(out + (size_t)idx * 6);
    if (nv <= 0) {
        float2 z = make_float2(0.f, 0.f);
        o[0] = z; o[1] = z; o[2] = z;
        return;
    }
    unsigned jj = (unsigned)j % (unsigned)nv;
    int src = valid[((size_t)b << 16) + jj];
    const float2* p = (const float2*)(pts + ((size_t)(b << 16) + (size_t)src) * 6);
    o[0] = p[0]; o[1] = p[1]; o[2] = p[2];
}

extern "C" void kernel_launch(void* const* d_in, const int* in_sizes, int n_in,
                              void* d_out, int out_size, void* d_ws, size_t ws_size,
                              hipStream_t stream) {
    const float* pts = (const float*)d_in[0];
    float* out = (float*)d_out;

    const size_t MB = 1024ull * 1024ull;
    float* mind    = (float*)d_ws;                          // 16 MB
    int*   valid   = (int*)((char*)d_ws + 16 * MB);         // 16 MB
    float* partV   = (float*)((char*)d_ws + 32 * MB);       // 64 KB
    int*   partI   = (int*)((char*)d_ws + 32 * MB + 64 * 1024);   // 64 KB
    float* cur     = (float*)((char*)d_ws + 32 * MB + 128 * 1024); // 768 B
    int*   numvalid= (int*)((char*)d_ws + 32 * MB + 132 * 1024);   // 256 B
    float* pxyz    = (float*)((char*)d_ws + 33 * MB);       // 48 MB (optional)

    const bool pack = ws_size >= 33 * MB + (size_t)BB * NN * 3 * sizeof(float);
    const float* xyz = pack ? (const float*)pxyz : pts;
    const int stride = pack ? 3 : 6;

    // FPS: init (center 0 = point 0) + 3 x (reduce -> update)
    fps_init_kernel<<<BB * BPB, TPB, 0, stream>>>(pts, mind, pack ? pxyz : nullptr,
                                                  partV, partI);
    fps_reduce_kernel<<<BB, TPB, 0, stream>>>(partV, partI, xyz, stride, cur);
    for (int it = 1; it < NP; ++it) {
        fps_upd_kernel<<<BB * BPB, TPB, 0, stream>>>(xyz, stride, cur, mind,
                                                     partV, partI, it < NP - 1 ? 1 : 0);
        if (it < NP - 1)
            fps_reduce_kernel<<<BB, TPB, 0, stream>>>(partV, partI, xyz, stride, cur);
    }

    compact_kernel<<<BB, 1024, 0, stream>>>(mind, valid, numvalid);
    gather_kernel<<<(BB * NN) / 256, 256, 0, stream>>>(pts, valid, numvalid, out);
}

// Round 5
// 278.291 us; speedup vs baseline: 1.6120x; 1.0789x over previous
//
#include <hip/hip_runtime.h>
#include <stdint.h>

#define NN 65536
#define BB 64
#define TPB 256
#define BLKS_PER_B 16
#define GRID (BB * BLKS_PER_B)
#define PPB 4096      // points per block
#define LPT 16        // iterations per thread (PPB / TPB)

// Exact-fp32 squared distance, matching numpy's ((dx*dx + dy*dy) + dz*dz)
// with no FMA contraction (rn intrinsics are never fused).
__device__ __forceinline__ float sqdist(float x, float y, float z,
                                        float cx, float cy, float cz) {
    float dx = __fsub_rn(x, cx);
    float dy = __fsub_rn(y, cy);
    float dz = __fsub_rn(z, cz);
    return __fadd_rn(__fadd_rn(__fmul_rn(dx, dx), __fmul_rn(dy, dy)),
                     __fmul_rn(dz, dz));
}

// Packed argmax key: (fp32 bits << 32) | (0xFFFFFFFF - index).
// Distances >= 0 so fp32 bit pattern order == value order; ~index makes
// the u64 max prefer the SMALLEST index on value ties (np.argmax semantics).
__device__ __forceinline__ unsigned long long pack_key(float v, int i) {
    return ((unsigned long long)__float_as_uint(v) << 32) |
           (unsigned long long)(0xFFFFFFFFu - (unsigned)i);
}

// FPS pass NC (1..3): recompute min distance over centers 0..NC-1 straight
// from pts (min is associative -> bitwise identical to the sequential chain),
// block argmax, then ONE device-scope atomicMax per block. No fences needed.
template<int NC>
__global__ __launch_bounds__(TPB) void fps_pass(
        const float* __restrict__ pts, unsigned long long* best) {
    const int gb = blockIdx.x;
    const int b = gb >> 4, blk = gb & 15;
    const int tid = threadIdx.x;
    const int lane = tid & 63, wid = tid >> 6;
    const float* base = pts + (size_t)b * NN * 6;

    // centers: c0 = point 0; c1..c{NC-1} decoded from previous passes' keys
    float cx[NC], cy[NC], cz[NC];
    cx[0] = base[0]; cy[0] = base[1]; cz[0] = base[2];
    #pragma unroll
    for (int k = 1; k < NC; ++k) {
        unsigned long long key = best[(k - 1) * BB + b];   // prev kernel wrote it
        int idx = (int)(0xFFFFFFFFu - (unsigned)(key & 0xFFFFFFFFu));
        const float* p = base + (size_t)idx * 6;
        cx[k] = p[0]; cy[k] = p[1]; cz[k] = p[2];
    }

    float bestv = -1.0f; int besti = 0x7fffffff;
    #pragma unroll
    for (int l = 0; l < LPT; ++l) {
        const int p = blk * PPB + l * TPB + tid;   // coalesced across lanes
        const float* q = base + (size_t)p * 6;
        float2 xy = *(const float2*)q;             // p*24 is 8B-aligned
        float  zz = q[2];
        float d = sqdist(xy.x, xy.y, zz, cx[0], cy[0], cz[0]);
        #pragma unroll
        for (int k = 1; k < NC; ++k)
            d = fminf(d, sqdist(xy.x, xy.y, zz, cx[k], cy[k], cz[k]));
        if (d > bestv) { bestv = d; besti = p; }   // ascending p -> earliest idx
    }
    unsigned long long key = pack_key(bestv, besti);
    #pragma unroll
    for (int off = 32; off > 0; off >>= 1) {
        unsigned long long ok = __shfl_down(key, off, 64);
        if (ok > key) key = ok;
    }
    __shared__ unsigned long long s_k[4];
    if (lane == 0) s_k[wid] = key;
    __syncthreads();
    if (tid == 0) {
        unsigned long long bk = s_k[0];
        #pragma unroll
        for (int w = 1; w < 4; ++w) bk = (s_k[w] > bk) ? s_k[w] : bk;
        atomicMax(&best[(NC - 1) * BB + b], bk);   // device-scope, coherent
    }
}

// Final pass: min over all 4 centers -> keep bits -> ballot -> mask words.
// Pure data-parallel; compaction happens in the NEXT kernel (boundary = flush).
__global__ __launch_bounds__(TPB) void fps_final(
        const float* __restrict__ pts, const unsigned long long* __restrict__ best,
        uint64_t* __restrict__ masks) {
    const int gb = blockIdx.x;
    const int b = gb >> 4, blk = gb & 15;
    const int tid = threadIdx.x;
    const int lane = tid & 63, wid = tid >> 6;
    const float* base = pts + (size_t)b * NN * 6;

    float cx[4], cy[4], cz[4];
    cx[0] = base[0]; cy[0] = base[1]; cz[0] = base[2];
    #pragma unroll
    for (int k = 1; k < 4; ++k) {
        unsigned long long key = best[(k - 1) * BB + b];
        int idx = (int)(0xFFFFFFFFu - (unsigned)(key & 0xFFFFFFFFu));
        const float* p = base + (size_t)idx * 6;
        cx[k] = p[0]; cy[k] = p[1]; cz[k] = p[2];
    }
    uint64_t* mb = masks + (size_t)b * 1024;

    #pragma unroll
    for (int l = 0; l < LPT; ++l) {
        const int p = blk * PPB + l * TPB + tid;
        const float* q = base + (size_t)p * 6;
        float2 xy = *(const float2*)q;
        float  zz = q[2];
        float d = sqdist(xy.x, xy.y, zz, cx[0], cy[0], cz[0]);
        #pragma unroll
        for (int k = 1; k < 4; ++k)
            d = fminf(d, sqdist(xy.x, xy.y, zz, cx[k], cy[k], cz[k]));
        // sqrt_rn is monotone & correctly rounded: sqrt(min d^2)==min(norm)
        int keep = (__fsqrt_rn(d) >= 0.2f) ? 1 : 0;
        uint64_t m = __ballot(keep);               // bit L == point p0 + L
        if (lane == 0) mb[blk * 64 + l * 4 + wid] = m;
    }
}

// Stable compaction: one block per batch; thread t owns mask words 4t..4t+3
// == points 256t..256t+255, so scan order == original index order.
__global__ __launch_bounds__(TPB) void compact_kernel(
        const uint64_t* __restrict__ masks, int* __restrict__ valid,
        int* __restrict__ numvalid) {
    const int b = blockIdx.x;
    const int tid = threadIdx.x;
    const int lane = tid & 63, wid = tid >> 6;
    const uint64_t* mb = masks + (size_t)b * 1024;
    uint64_t w0 = mb[tid * 4 + 0], w1 = mb[tid * 4 + 1];
    uint64_t w2 = mb[tid * 4 + 2], w3 = mb[tid * 4 + 3];
    int cnt4 = __popcll(w0) + __popcll(w1) + __popcll(w2) + __popcll(w3);
    int incl = cnt4;
    #pragma unroll
    for (int off = 1; off < 64; off <<= 1) {
        int v = __shfl_up(incl, off, 64);
        if (lane >= off) incl += v;
    }
    __shared__ int s_ws[4], s_wo[4];
    if (lane == 63) s_ws[wid] = incl;
    __syncthreads();
    if (tid == 0) {
        int run = 0;
        #pragma unroll
        for (int w = 0; w < 4; ++w) { s_wo[w] = run; run += s_ws[w]; }
        numvalid[b] = run;
    }
    __syncthreads();
    int pos = s_wo[wid] + incl - cnt4;             // exclusive offset
    int* vb = valid + ((size_t)b << 16);
    const int pbase = tid * 256;
    uint64_t ws[4] = { w0, w1, w2, w3 };
    #pragma unroll
    for (int wdx = 0; wdx < 4; ++wdx) {
        uint64_t m = ws[wdx];
        int pb = pbase + wdx * 64;
        while (m) {
            int k = __builtin_ctzll(m);
            m &= m - 1;
            vb[pos++] = pb + k;
        }
    }
}

// Cyclic gather of kept points into the output.
__global__ __launch_bounds__(256) void gather_kernel(
        const float* __restrict__ pts, const int* __restrict__ valid,
        const int* __restrict__ numvalid, float* __restrict__ out) {
    const int idx = blockIdx.x * 256 + threadIdx.x;  // over B*N
    const int b = idx >> 16;
    const int j = idx & (NN - 1);
    const int nv = numvalid[b];
    float2* o = (float2*)(out + (size_t)idx * 6);
    if (nv <= 0) {
        float2 z = make_float2(0.f, 0.f);
        o[0] = z; o[1] = z; o[2] = z;
        return;
    }
    unsigned jj = (unsigned)j % (unsigned)nv;
    int src = valid[((size_t)b << 16) + jj];
    const float2* p = (const float2*)(pts + ((size_t)(b << 16) + (size_t)src) * 6);
    o[0] = p[0]; o[1] = p[1]; o[2] = p[2];
}

extern "C" void kernel_launch(void* const* d_in, const int* in_sizes, int n_in,
                              void* d_out, int out_size, void* d_ws, size_t ws_size,
                              hipStream_t stream) {
    const float* pts = (const float*)d_in[0];
    float* out = (float*)d_out;

    // workspace layout
    unsigned long long* best = (unsigned long long*)d_ws;            // 1.5 KB
    int*      numvalid = (int*)((char*)d_ws + (4 << 10));            // 256 B
    uint64_t* masks    = (uint64_t*)((char*)d_ws + (64 << 10));      // 512 KB
    int*      valid    = (int*)((char*)d_ws + (1 << 20));            // 16 MB

    hipMemsetAsync(best, 0, 3 * BB * sizeof(unsigned long long), stream);

    fps_pass<1><<<GRID, TPB, 0, stream>>>(pts, best);
    fps_pass<2><<<GRID, TPB, 0, stream>>>(pts, best);
    fps_pass<3><<<GRID, TPB, 0, stream>>>(pts, best);
    fps_final<<<GRID, TPB, 0, stream>>>(pts, best, masks);
    compact_kernel<<<BB, TPB, 0, stream>>>(masks, valid, numvalid);
    gather_kernel<<<(BB * NN) / 256, 256, 0, stream>>>(pts, valid, numvalid, out);
}

// Round 6
// 246.957 us; speedup vs baseline: 1.8166x; 1.1269x over previous
//
#include <hip/hip_runtime.h>
#include <stdint.h>

#define NN 65536
#define BB 64
#define TPB 256

// FPS pass geometry: 32 blocks/batch, 2048 points/block, 8 iters/thread
#define FBPB 32
#define FGRID (BB * FBPB)   // 2048 blocks = 8/CU
#define FPPB 2048
#define FLPT 8

// Gather geometry: 16 blocks/batch, 4096 rows/block, 16 rows/thread
#define GBPB 16
#define GGRID (BB * GBPB)   // 1024 blocks
#define GLPT 16

// Exact-fp32 squared distance, matching numpy's ((dx*dx + dy*dy) + dz*dz)
// with no FMA contraction (rn intrinsics are never fused).
__device__ __forceinline__ float sqdist(float x, float y, float z,
                                        float cx, float cy, float cz) {
    float dx = __fsub_rn(x, cx);
    float dy = __fsub_rn(y, cy);
    float dz = __fsub_rn(z, cz);
    return __fadd_rn(__fadd_rn(__fmul_rn(dx, dx), __fmul_rn(dy, dy)),
                     __fmul_rn(dz, dz));
}

// Packed argmax key: (fp32 bits << 32) | (0xFFFFFFFF - index).
// Distances >= 0 so fp32 bit order == value order; ~index makes u64-max
// prefer the SMALLEST index on value ties (np.argmax semantics).
__device__ __forceinline__ unsigned long long pack_key(float v, int i) {
    return ((unsigned long long)__float_as_uint(v) << 32) |
           (unsigned long long)(0xFFFFFFFFu - (unsigned)i);
}

__device__ __forceinline__ int key_idx(unsigned long long key) {
    return (int)(0xFFFFFFFFu - (unsigned)(key & 0xFFFFFFFFu));
}

// Reduce the 32 partial keys of batch b from pass array `a` (redundantly per
// thread — 32 broadcast loads, cheap) -> winning point index.
__device__ __forceinline__ int reduce_part(const unsigned long long* partKey,
                                           int a, int b) {
    const unsigned long long* s = partKey + a * FGRID + b * FBPB;
    unsigned long long bk = s[0];
    #pragma unroll
    for (int w = 1; w < FBPB; ++w) bk = (s[w] > bk) ? s[w] : bk;
    return key_idx(bk);
}

// FPS pass NC (1..3): centers 0..NC-1 (c0 = point 0; ck from reducing pass k's
// partials), recompute min-distance from pts (fp-min is associative ->
// bitwise identical to the sequential jnp.minimum chain), block argmax,
// plain store of this block's best key. No atomics, no memset needed.
template<int NC>
__global__ __launch_bounds__(TPB) void fps_pass(
        const float* __restrict__ pts, unsigned long long* partKey) {
    const int gb = blockIdx.x;
    const int b = gb >> 5, blk = gb & 31;
    const int tid = threadIdx.x;
    const int lane = tid & 63, wid = tid >> 6;
    const float* base = pts + (size_t)b * NN * 6;

    float cx[NC], cy[NC], cz[NC];
    cx[0] = base[0]; cy[0] = base[1]; cz[0] = base[2];
    #pragma unroll
    for (int k = 1; k < NC; ++k) {
        int idx = reduce_part(partKey, k - 1, b);
        const float* p = base + (size_t)idx * 6;
        cx[k] = p[0]; cy[k] = p[1]; cz[k] = p[2];
    }

    float bestv = -1.0f; int besti = 0x7fffffff;
    #pragma unroll
    for (int l = 0; l < FLPT; ++l) {
        const int p = blk * FPPB + l * TPB + tid;   // coalesced across lanes
        const float* q = base + (size_t)p * 6;
        float2 xy = *(const float2*)q;              // p*24 is 8B-aligned
        float  zz = q[2];
        float d = sqdist(xy.x, xy.y, zz, cx[0], cy[0], cz[0]);
        #pragma unroll
        for (int k = 1; k < NC; ++k)
            d = fminf(d, sqdist(xy.x, xy.y, zz, cx[k], cy[k], cz[k]));
        if (d > bestv) { bestv = d; besti = p; }    // ascending p -> earliest
    }
    unsigned long long key = pack_key(bestv, besti);
    #pragma unroll
    for (int off = 32; off > 0; off >>= 1) {
        unsigned long long ok = __shfl_down(key, off, 64);
        if (ok > key) key = ok;
    }
    __shared__ unsigned long long s_k[4];
    if (lane == 0) s_k[wid] = key;
    __syncthreads();
    if (tid == 0) {
        unsigned long long bk = s_k[0];
        #pragma unroll
        for (int w = 1; w < 4; ++w) bk = (s_k[w] > bk) ? s_k[w] : bk;
        partKey[(NC - 1) * FGRID + gb] = bk;        // own slot: plain store
    }
}

// Final pass: min over all 4 centers -> keep bits -> ballot -> mask words.
__global__ __launch_bounds__(TPB) void fps_final(
        const float* __restrict__ pts,
        const unsigned long long* __restrict__ partKey,
        uint64_t* __restrict__ masks) {
    const int gb = blockIdx.x;
    const int b = gb >> 5, blk = gb & 31;
    const int tid = threadIdx.x;
    const int lane = tid & 63, wid = tid >> 6;
    const float* base = pts + (size_t)b * NN * 6;

    float cx[4], cy[4], cz[4];
    cx[0] = base[0]; cy[0] = base[1]; cz[0] = base[2];
    #pragma unroll
    for (int k = 1; k < 4; ++k) {
        int idx = reduce_part(partKey, k - 1, b);
        const float* p = base + (size_t)idx * 6;
        cx[k] = p[0]; cy[k] = p[1]; cz[k] = p[2];
    }
    uint64_t* mb = masks + (size_t)b * 1024;

    #pragma unroll
    for (int l = 0; l < FLPT; ++l) {
        const int p = blk * FPPB + l * TPB + tid;
        const float* q = base + (size_t)p * 6;
        float2 xy = *(const float2*)q;
        float  zz = q[2];
        float d = sqdist(xy.x, xy.y, zz, cx[0], cy[0], cz[0]);
        #pragma unroll
        for (int k = 1; k < 4; ++k)
            d = fminf(d, sqdist(xy.x, xy.y, zz, cx[k], cy[k], cz[k]));
        // sqrt_rn is monotone & correctly rounded: sqrt(min d^2)==min(norm)
        int keep = (__fsqrt_rn(d) >= 0.2f) ? 1 : 0;
        uint64_t m = __ballot(keep);                // bit L == point p0 + L
        if (lane == 0) mb[blk * 32 + l * 4 + wid] = m;
    }
}

// Fused compaction + cyclic gather. 16 blocks/batch; each loads the batch's
// 1024 mask words to LDS, scans to per-word exclusive prefix (== stable
// compaction order), then rank-selects the source point for each output row.
__global__ __launch_bounds__(TPB) void gather_kernel(
        const float* __restrict__ pts, const uint64_t* __restrict__ masks,
        float* __restrict__ out) {
    const int gb = blockIdx.x;
    const int b = gb >> 4, blk = gb & 15;
    const int tid = threadIdx.x;
    const int lane = tid & 63, wid = tid >> 6;
    __shared__ uint64_t s_m[1024];
    __shared__ int s_pre[1024];
    __shared__ int s_ws[4], s_wo[4];
    __shared__ int s_nv;

    const uint64_t* mb = masks + (size_t)b * 1024;
    uint64_t w[4];
    int cnt = 0;
    #pragma unroll
    for (int k = 0; k < 4; ++k) {
        w[k] = mb[tid * 4 + k];
        s_m[tid * 4 + k] = w[k];
        cnt += __popcll(w[k]);
    }
    // block exclusive scan of per-thread counts (thread order == word order)
    int incl = cnt;
    #pragma unroll
    for (int off = 1; off < 64; off <<= 1) {
        int v = __shfl_up(incl, off, 64);
        if (lane >= off) incl += v;
    }
    if (lane == 63) s_ws[wid] = incl;
    __syncthreads();
    if (tid == 0) {
        int run = 0;
        #pragma unroll
        for (int q = 0; q < 4; ++q) { s_wo[q] = run; run += s_ws[q]; }
        s_nv = run;
    }
    __syncthreads();
    int run = s_wo[wid] + incl - cnt;               // exclusive offset, word 4t
    #pragma unroll
    for (int k = 0; k < 4; ++k) {
        s_pre[tid * 4 + k] = run;
        run += __popcll(w[k]);
    }
    __syncthreads();

    const int nv = s_nv;
    const float* baseP = pts + (size_t)b * NN * 6;
    float* ob = out + (size_t)b * NN * 6;

    if (nv <= 0) {
        float2 zz = make_float2(0.f, 0.f);
        #pragma unroll
        for (int l = 0; l < GLPT; ++l) {
            int j = blk * 4096 + l * TPB + tid;
            float2* o = (float2*)(ob + (size_t)j * 6);
            o[0] = zz; o[1] = zz; o[2] = zz;
        }
        return;
    }

    #pragma unroll
    for (int l = 0; l < GLPT; ++l) {
        int j = blk * 4096 + l * TPB + tid;         // coalesced across lanes
        int jj = (int)((unsigned)j % (unsigned)nv); // rank of source point
        // largest word wd with s_pre[wd] <= jj  (s_pre[0]==0 <= jj always)
        int wd = 0;
        #pragma unroll
        for (int s = 512; s > 0; s >>= 1) {
            int cand = wd + s;
            if (cand < 1024 && s_pre[cand] <= jj) wd = cand;
        }
        int r = jj - s_pre[wd];
        uint64_t m = s_m[wd];
        // select r-th (0-based, from LSB) set bit of m
        int bit = 0;
        int c = __popcll(m & 0xFFFFFFFFull);
        if (r >= c) { r -= c; m >>= 32; bit += 32; }
        c = __popcll(m & 0xFFFFull);
        if (r >= c) { r -= c; m >>= 16; bit += 16; }
        c = __popcll(m & 0xFFull);
        if (r >= c) { r -= c; m >>= 8; bit += 8; }
        c = __popcll(m & 0xFull);
        if (r >= c) { r -= c; m >>= 4; bit += 4; }
        c = __popcll(m & 0x3ull);
        if (r >= c) { r -= c; m >>= 2; bit += 2; }
        if (r >= (int)(m & 1ull)) { bit += 1; }
        int src = wd * 64 + bit;
        const float2* p = (const float2*)(baseP + (size_t)src * 6);
        float2* o = (float2*)(ob + (size_t)j * 6);
        float2 r0 = p[0], r1 = p[1], r2 = p[2];
        o[0] = r0; o[1] = r1; o[2] = r2;
    }
}

extern "C" void kernel_launch(void* const* d_in, const int* in_sizes, int n_in,
                              void* d_out, int out_size, void* d_ws, size_t ws_size,
                              hipStream_t stream) {
    const float* pts = (const float*)d_in[0];
    float* out = (float*)d_out;

    // workspace layout (all fully written before read each call; no memset)
    unsigned long long* partKey = (unsigned long long*)d_ws;      // 3*2048*8 = 48 KB
    uint64_t* masks = (uint64_t*)((char*)d_ws + (64 << 10));      // 512 KB

    fps_pass<1><<<FGRID, TPB, 0, stream>>>(pts, partKey);
    fps_pass<2><<<FGRID, TPB, 0, stream>>>(pts, partKey);
    fps_pass<3><<<FGRID, TPB, 0, stream>>>(pts, partKey);
    fps_final<<<FGRID, TPB, 0, stream>>>(pts, partKey, masks);
    gather_kernel<<<GGRID, TPB, 0, stream>>>(pts, masks, out);
}